// Round 8
// baseline (602.359 us; speedup 1.0000x reference)
//
#include <hip/hip_runtime.h>
#include <hip/hip_fp16.h>

#define N_NODES 500000
#define N_EDGES 5000000
#define D 16
#define BSH 9
#define BSZ 512                          // nodes per dst bucket
#define NB ((N_NODES + BSZ - 1) / BSZ)   // 977 dst buckets
#define CH 16384                         // edges per place-block chunk
#define PBLK ((N_EDGES + CH - 1) / CH)   // 306 blocks
#define NCK 8                            // 8 chunks x 2 dims fp16 -> 2MB tables
#define SLP 17                           // LDS slice stride (pad 16 -> 17)
#define SRCAP 5632                       // staged recs per bucket (7.2 sigma)

// ---- K0: x -> 8 chunk-major fp16 tables: xt[c][node] = dims (2c, 2c+1) ----
__global__ __launch_bounds__(256) void conv_k(const float* __restrict__ x,
                                              unsigned* __restrict__ xt) {
    int i = blockIdx.x * blockDim.x + threadIdx.x;
    if (i >= N_NODES) return;
    const float2* xr = (const float2*)(x + (size_t)i * D);
#pragma unroll
    for (int c = 0; c < NCK; ++c) {
        float2 v = xr[c];
        __half2 h = __floats2half2_rn(v.x, v.y);
        xt[(size_t)c * N_NODES + i] = *reinterpret_cast<unsigned*>(&h);
    }
}

// ---- K1: dst-bucket histogram (LDS-privatized) ----------------------------
__global__ __launch_bounds__(256) void hist_k(const int* __restrict__ edst,
                                              int* __restrict__ bhist) {
    __shared__ int h[NB];
    for (int i = threadIdx.x; i < NB; i += 256) h[i] = 0;
    __syncthreads();
    int stride = gridDim.x * blockDim.x;
    for (int e = blockIdx.x * blockDim.x + threadIdx.x; e < N_EDGES; e += stride)
        atomicAdd(&h[edst[e] >> BSH], 1);
    __syncthreads();
    for (int i = threadIdx.x; i < NB; i += 256)
        if (h[i]) atomicAdd(&bhist[i], h[i]);
}

// ---- K2: exclusive scan of bucket totals (1 block) ------------------------
__global__ void scan_k(const int* __restrict__ bhist, int* __restrict__ boff,
                       int* __restrict__ cursor) {
    __shared__ int s[1024];
    int t = threadIdx.x;
    int v = (t < NB) ? bhist[t] : 0;
    s[t] = v; __syncthreads();
    for (int off = 1; off < 1024; off <<= 1) {
        int u = (t >= off) ? s[t - off] : 0;
        __syncthreads(); s[t] += u; __syncthreads();
    }
    if (t < NB) { int ex = s[t] - v; boff[t] = ex; cursor[t] = ex; }
    if (t == 0) boff[NB] = N_EDGES;
}

// ---- K3: bulk-reserve counting-sort placement -----------------------------
__global__ __launch_bounds__(256) void place_k(const int* __restrict__ esrc,
                                               const int* __restrict__ edst,
                                               int* __restrict__ cursor,
                                               unsigned* __restrict__ rec) {
    __shared__ int lc[NB];
    int t = threadIdx.x;
    for (int i = t; i < NB; i += 256) lc[i] = 0;
    __syncthreads();
    int e0 = blockIdx.x * CH;
    int e1 = e0 + CH; if (e1 > N_EDGES) e1 = N_EDGES;
    for (int e = e0 + t; e < e1; e += 256)
        atomicAdd(&lc[edst[e] >> BSH], 1);
    __syncthreads();
    for (int i = t; i < NB; i += 256) {
        int c = lc[i];
        if (c) lc[i] = atomicAdd(&cursor[i], c);
    }
    __syncthreads();
    for (int e = e0 + t; e < e1; e += 256) {
        int dd = edst[e];
        int p = atomicAdd(&lc[dd >> BSH], 1);
        rec[p] = ((unsigned)(dd & (BSZ - 1)) << 19) | (unsigned)esrc[e];
    }
}

// ---- K4: LDS-persistent recs, 8 chunk passes over 2MB L2-resident tables --
// Recs staged into LDS ONCE; the only global traffic in the pass loop is the
// 4B random gather into the 2MB chunk table. Full 16-dim slice accumulated
// in LDS; epilogue (mean + GEMVs) fused.
__global__ __launch_bounds__(512, 2) void reduce_k(
    const float* __restrict__ x, const unsigned* __restrict__ xt,
    const unsigned* __restrict__ rec, const int* __restrict__ boff,
    const float* __restrict__ Wl, const float* __restrict__ bl,
    const float* __restrict__ Wr, float* __restrict__ out) {
    __shared__ float slice[BSZ * SLP];   // 34.8KB, stride-17 padded
    __shared__ unsigned srec[SRCAP];     // 22.5KB
    __shared__ int scnt[BSZ];            // 2KB
    int t = threadIdx.x;
    for (int i = t; i < BSZ * SLP; i += 512) slice[i] = 0.f;
    scnt[t] = 0;                          // blockDim == BSZ
    __syncthreads();

    int b = blockIdx.x;
    int beg = boff[b], end = boff[b + 1];
    int n = end - beg;
    int ns = n < SRCAP ? n : SRCAP;

    for (int i = t; i < ns; i += 512) {
        unsigned rc = __builtin_nontemporal_load(&rec[beg + i]);
        srec[i] = rc;
        atomicAdd(&scnt[rc >> 19], 1);
    }
    for (int i = SRCAP + t; i < n; i += 512) {   // overflow guard (empty in practice)
        unsigned rc = __builtin_nontemporal_load(&rec[beg + i]);
        atomicAdd(&scnt[rc >> 19], 1);
    }
    __syncthreads();

#pragma unroll 1
    for (int c = 0; c < NCK; ++c) {
        const unsigned* tab = xt + (size_t)c * N_NODES;
        for (int i = t; i < ns; i += 512) {
            unsigned rc = srec[i];
            unsigned u = tab[rc & 0x7FFFFu];          // 4B gather, L2-resident
            __half2 h = *reinterpret_cast<__half2*>(&u);
            float2 f = __half22float2(h);
            int base = (int)(rc >> 19) * SLP + 2 * c;
            atomicAdd(&slice[base], f.x);
            atomicAdd(&slice[base + 1], f.y);
        }
        for (int i = SRCAP + t; i < n; i += 512) {    // overflow guard
            unsigned rc = __builtin_nontemporal_load(&rec[beg + i]);
            unsigned u = tab[rc & 0x7FFFFu];
            __half2 h = *reinterpret_cast<__half2*>(&u);
            float2 f = __half22float2(h);
            int base = (int)(rc >> 19) * SLP + 2 * c;
            atomicAdd(&slice[base], f.x);
            atomicAdd(&slice[base + 1], f.y);
        }
        __syncthreads();                  // phase-lock the chunk tables
    }

    // epilogue: mean + out = mean@Wl^T + bl + x@Wr^T (16-lane-group GEMV)
    int d = t & 15, g = t >> 4;
    float wl[D], wr[D];
    const float4* wl4 = (const float4*)(Wl + d * D);
    const float4* wr4 = (const float4*)(Wr + d * D);
#pragma unroll
    for (int q = 0; q < 4; ++q) {
        float4 a = wl4[q], b2 = wr4[q];
        wl[4*q]=a.x; wl[4*q+1]=a.y; wl[4*q+2]=a.z; wl[4*q+3]=a.w;
        wr[4*q]=b2.x; wr[4*q+1]=b2.y; wr[4*q+2]=b2.z; wr[4*q+3]=b2.w;
    }
    float bb = bl[d];
    int node0 = b << BSH;
    for (int nn = g; nn < BSZ; nn += 32) {
        int node = node0 + nn;
        if (node >= N_NODES) break;       // uniform within 16-lane group
        float m  = slice[nn * SLP + d] / fmaxf((float)scnt[nn], 1.f);
        float xv = x[node * D + d];
        float o  = bb;
#pragma unroll
        for (int k = 0; k < D; ++k)
            o += __shfl(m, k, 16) * wl[k] + __shfl(xv, k, 16) * wr[k];
        out[node * D + d] = o;
    }
}

// ===================== fallback (R1 atomic path, needs only 2MB ws) ========
__global__ void sage_scatter(const float* __restrict__ x, const int* __restrict__ esrc,
                             const int* __restrict__ edst, float* __restrict__ agg,
                             float* __restrict__ cnt) {
    long long gid = (long long)blockIdx.x * blockDim.x + threadIdx.x;
    long long e = gid >> 4;
    int d = (int)(gid & 15);
    if (e >= N_EDGES) return;
    atomicAdd(&agg[(long long)edst[e] * D + d], x[(long long)esrc[e] * D + d]);
    if (d == 0) atomicAdd(&cnt[edst[e]], 1.0f);
}

__global__ void sage_finalize(const float* __restrict__ x, float* __restrict__ agg_out,
                              const float* __restrict__ cnt, const float* __restrict__ W_l,
                              const float* __restrict__ b_l, const float* __restrict__ W_r) {
    __shared__ float sWl[D * D], sWr[D * D], sb[D];
    int tid = threadIdx.x;
    if (tid < D * D) { sWl[tid] = W_l[tid]; sWr[tid] = W_r[tid]; }
    if (tid < D) sb[tid] = b_l[tid];
    __syncthreads();
    int i = blockIdx.x * blockDim.x + tid;
    if (i >= N_NODES) return;
    float inv = 1.0f / fmaxf(cnt[i], 1.0f);
    float m[D], xv[D];
    const float4* ap = (const float4*)(agg_out + (long long)i * D);
    const float4* xp = (const float4*)(x + (long long)i * D);
#pragma unroll
    for (int q = 0; q < 4; ++q) {
        float4 a = ap[q], b = xp[q];
        m[4*q]=a.x*inv; m[4*q+1]=a.y*inv; m[4*q+2]=a.z*inv; m[4*q+3]=a.w*inv;
        xv[4*q]=b.x; xv[4*q+1]=b.y; xv[4*q+2]=b.z; xv[4*q+3]=b.w;
    }
    float o[D];
#pragma unroll
    for (int oo = 0; oo < D; ++oo) {
        float a2 = sb[oo];
#pragma unroll
        for (int k = 0; k < D; ++k) a2 += m[k]*sWl[oo*D+k] + xv[k]*sWr[oo*D+k];
        o[oo] = a2;
    }
    float4* op = (float4*)(agg_out + (long long)i * D);
#pragma unroll
    for (int q = 0; q < 4; ++q)
        op[q] = make_float4(o[4*q], o[4*q+1], o[4*q+2], o[4*q+3]);
}

// ===================== launch =====================
extern "C" void kernel_launch(void* const* d_in, const int* in_sizes, int n_in,
                              void* d_out, int out_size, void* d_ws, size_t ws_size,
                              hipStream_t stream) {
    const float* x   = (const float*)d_in[0];
    const int*   ei  = (const int*)d_in[1];
    const float* W_l = (const float*)d_in[2];
    const float* b_l = (const float*)d_in[3];
    const float* W_r = (const float*)d_in[4];
    const int* esrc = ei;
    const int* edst = ei + N_EDGES;
    float* out = (float*)d_out;

    // ws layout: xt (16MB) | rec (20MB) | bhist | boff | cursor
    size_t xt_b  = (size_t)NCK * N_NODES * 4;
    size_t rec_b = (size_t)N_EDGES * 4;
    size_t need  = xt_b + rec_b + (size_t)(3 * NB + 1) * 4;

    if (ws_size >= need) {
        unsigned* xt     = (unsigned*)d_ws;
        unsigned* rec    = (unsigned*)((char*)d_ws + xt_b);
        int*      bhist  = (int*)((char*)d_ws + xt_b + rec_b);
        int*      boff   = bhist + NB;
        int*      cursor = boff + (NB + 1);

        hipMemsetAsync(bhist, 0, (size_t)NB * 4, stream);
        conv_k<<<(N_NODES + 255) / 256, 256, 0, stream>>>(x, xt);
        hist_k<<<512, 256, 0, stream>>>(edst, bhist);
        scan_k<<<1, 1024, 0, stream>>>(bhist, boff, cursor);
        place_k<<<PBLK, 256, 0, stream>>>(esrc, edst, cursor, rec);
        reduce_k<<<NB, 512, 0, stream>>>(x, xt, rec, boff, W_l, b_l, W_r, out);
    } else {
        float* cntf = (float*)d_ws;
        hipMemsetAsync(out, 0, (size_t)N_NODES * D * sizeof(float), stream);
        hipMemsetAsync(cntf, 0, (size_t)N_NODES * sizeof(float), stream);
        long long total = (long long)N_EDGES * D;
        sage_scatter<<<(unsigned)((total + 255) / 256), 256, 0, stream>>>(x, esrc, edst, out, cntf);
        sage_finalize<<<(N_NODES + 255) / 256, 256, 0, stream>>>(x, out, cntf, W_l, b_l, W_r);
    }
}